// Round 4
// baseline (304.613 us; speedup 1.0000x reference)
//
#include <hip/hip_runtime.h>
#include <cstdint>

#define LON 1440
#define LAT 721
#define NB  32
#define NW32 45      // 1440/32 mask words per row
#define NV   360     // float4 chunks per row
#define RPB 4        // rows (waves) per block
#define BS  (RPB * 64)

typedef float f32x4 __attribute__((ext_vector_type(4)));

__device__ __forceinline__ bool is_nan_f(float v) {
    return (__float_as_uint(v) & 0x7fffffffu) > 0x7f800000u;
}

__device__ __forceinline__ unsigned pack_nib(f32x4 v) {
    return (!is_nan_f(v.x) ? 1u : 0u) | (!is_nan_f(v.y) ? 2u : 0u)
         | (!is_nan_f(v.z) ? 4u : 0u) | (!is_nan_f(v.w) ? 8u : 0u);
}

// One WAVE per (b,h) row — no __syncthreads anywhere. Each lane holds the
// row's 6 float4 chunks in registers; validity bitmask (45 u32 words) lives
// in a tiny per-wave LDS strip (wave-internal ds ordering via lgkmcnt only).
// Neighbor values for the lerp are gathered from global (L1/L2-hot).
__global__ __launch_bounds__(BS, 8) void fill_rows(const f32x4* __restrict__ sst4,
                                                   const float* __restrict__ sst,
                                                   f32x4*       __restrict__ out4,
                                                   unsigned char* __restrict__ rowflag) {
    __shared__ unsigned int msk[RPB][48];

    const int tid  = threadIdx.x;
    const int lane = tid & 63;
    const int wv   = tid >> 6;
    const int r    = blockIdx.x * RPB + wv;          // grid covers all rows exactly
    const size_t base4   = (size_t)r * NV;
    const size_t rowbase = (size_t)r * LON;

    // Load all 6 chunks (registers), pack validity nibbles.
    f32x4 sv[6];
    unsigned nib[6];
    #pragma unroll
    for (int k = 0; k < 6; ++k) {
        const int c = 64 * k + lane;
        if (c < NV) {
            sv[k] = sst4[base4 + c];
            nib[k] = pack_nib(sv[k]);
        } else {
            sv[k] = (f32x4){0.f, 0.f, 0.f, 0.f};
            nib[k] = 0u;
        }
    }

    // Build mask words: 8 consecutive lanes' nibbles -> one u32 word.
    #pragma unroll
    for (int k = 0; k < 6; ++k) {
        unsigned part = nib[k] << (4 * (lane & 7));
        part |= __shfl_xor(part, 1);
        part |= __shfl_xor(part, 2);
        part |= __shfl_xor(part, 4);
        const int w = 8 * k + (lane >> 3);
        if ((lane & 7) == 0 && w < NW32) msk[wv][w] = part;
    }
    // Wave-internal LDS visibility: whole-wave ds_write order + lgkmcnt.
    asm volatile("s_waitcnt lgkmcnt(0)" ::: "memory");

    // Row first/last valid index — uniform early-break scans (typ. 1 iter).
    int first = -1, last = -1;
    for (int w = 0; w < NW32; ++w) {
        unsigned mw = msk[wv][w];
        if (mw) { first = w * 32 + (__ffs(mw) - 1); break; }
    }
    if (first >= 0) {
        for (int w = NW32 - 1; w >= 0; --w) {
            unsigned mw = msk[wv][w];
            if (mw) { last = w * 32 + (31 - __clz(mw)); break; }
        }
    }
    if (lane == 0) rowflag[r] = (first >= 0) ? 1 : 0;

    // Fill NaN lanes and store.
    #pragma unroll
    for (int k = 0; k < 6; ++k) {
        const int c = 64 * k + lane;
        if (c >= NV) continue;
        f32x4 rv = sv[k];
        const unsigned nb = nib[k];
        if (first >= 0 && nb != 0xFu) {
            const int w = c >> 3;
            const unsigned mw = msk[wv][w];
            float res[4] = {rv.x, rv.y, rv.z, rv.w};
            #pragma unroll
            for (int j = 0; j < 4; ++j) {
                if (!(nb & (1u << j))) {
                    const int i = 4 * c + j;
                    const int bpos = i & 31;
                    // prev: highest valid <= i (wrap: last - LON)
                    unsigned bits = mw & (0xffffffffu >> (31 - bpos));
                    int ww = w;
                    while (bits == 0u && ww > 0) bits = msk[wv][--ww];
                    int prev = bits ? (ww * 32 + (31 - __clz(bits)))
                                    : (last - LON);
                    // next: lowest valid >= i (wrap: first + LON)
                    bits = mw & (0xffffffffu << bpos);
                    ww = w;
                    while (bits == 0u && ww < NW32 - 1) bits = msk[wv][++ww];
                    int nxt = bits ? (ww * 32 + (__ffs(bits) - 1))
                                   : (first + LON);
                    float t  = (float)(i - prev)
                             * __builtin_amdgcn_rcpf((float)(nxt - prev));
                    float sp = sst[rowbase + (prev < 0    ? prev + LON : prev)];
                    float sn = sst[rowbase + (nxt  >= LON ? nxt  - LON : nxt)];
                    res[j] = fmaf(t, sn - sp, sp);
                }
            }
            rv.x = res[0]; rv.y = res[1]; rv.z = res[2]; rv.w = res[3];
        }
        __builtin_nontemporal_store(rv, (f32x4*)&out4[base4 + c]);
    }
}

// One block per batch. Reduce lastrow from rowflag, then copy the last valid
// row's filled values into tail rows at NaN positions. Benchmark input:
// lastrow == LAT-1 -> early exit after the tiny reduction.
__global__ __launch_bounds__(256) void fill_tail(const float* __restrict__ sst,
                                                 float*       __restrict__ out,
                                                 const unsigned char* __restrict__ rowflag) {
    const int b = blockIdx.x;
    const int tid = threadIdx.x;
    __shared__ int red[256];
    int lr = -1;
    for (int h = tid; h < LAT; h += 256)
        if (rowflag[b * LAT + h]) lr = h;
    red[tid] = lr;
    __syncthreads();
    for (int off = 128; off > 0; off >>= 1) {
        if (tid < off) red[tid] = max(red[tid], red[tid + off]);
        __syncthreads();
    }
    lr = red[0];
    if (lr < 0 || lr == LAT - 1) return;
    const size_t fb = ((size_t)b * LAT + lr) * LON;
    for (int h = lr + 1; h < LAT; ++h) {
        const size_t base = ((size_t)b * LAT + h) * LON;
        for (int i = tid; i < LON; i += 256) {
            float svv = sst[base + i];
            out[base + i] = is_nan_f(svv) ? out[fb + i] : svv;
        }
    }
}

extern "C" void kernel_launch(void* const* d_in, const int* in_sizes, int n_in,
                              void* d_out, int out_size, void* d_ws, size_t ws_size,
                              hipStream_t stream) {
    const f32x4* sst4 = (const f32x4*)d_in[0];
    f32x4* out4 = (f32x4*)d_out;
    unsigned char* rowflag = (unsigned char*)d_ws;   // NB*LAT = 23072 bytes

    fill_rows<<<(NB * LAT) / RPB, BS, 0, stream>>>(sst4, (const float*)d_in[0],
                                                   out4, rowflag);
    fill_tail<<<NB, 256, 0, stream>>>((const float*)d_in[0], (float*)d_out, rowflag);
}

// Round 6
// 289.631 us; speedup vs baseline: 1.0517x; 1.0517x over previous
//
#include <hip/hip_runtime.h>
#include <cstdint>

#define LON 1440
#define LAT 721
#define NB  32
#define NW32 45      // 1440/32 mask words per row
#define NV   360     // float4 chunks per row
#define RPB 2        // rows (waves) per block
#define BS  (RPB * 64)

typedef float f32x4 __attribute__((ext_vector_type(4)));

__device__ __forceinline__ bool is_nan_f(float v) {
    return (__float_as_uint(v) & 0x7fffffffu) > 0x7f800000u;
}

__device__ __forceinline__ unsigned pack_nib(f32x4 v) {
    return (!is_nan_f(v.x) ? 1u : 0u) | (!is_nan_f(v.y) ? 2u : 0u)
         | (!is_nan_f(v.z) ? 4u : 0u) | (!is_nan_f(v.w) ? 8u : 0u);
}

// One WAVE per (b,h) row — no __syncthreads. Row values staged in a per-wave
// LDS strip (gathers are LDS-local); validity bitmask in per-wave LDS words.
// prev/next found via a 64-bit two-word window (clzll/ffsll) — the divergent
// word-scan loop only runs for NaN runs > 32 (never on this data).
__global__ __launch_bounds__(BS) void fill_rows(const f32x4* __restrict__ sst4,
                                                f32x4*       __restrict__ out4,
                                                unsigned char* __restrict__ rowflag) {
    __shared__ float        s[RPB][LON];
    __shared__ unsigned int msk[RPB][48];

    const int lane = threadIdx.x & 63;
    const int wv   = threadIdx.x >> 6;
    const int r    = blockIdx.x * RPB + wv;      // 23072 rows, grid exact
    const size_t base4 = (size_t)r * NV;

    // Load all 6 chunks into registers, mirror into LDS, pack validity.
    f32x4 sv[6];
    unsigned nib[6];
    #pragma unroll
    for (int k = 0; k < 6; ++k) {
        const int c = 64 * k + lane;
        if (c < NV) {
            sv[k] = sst4[base4 + c];
            ((f32x4*)s[wv])[c] = sv[k];
            nib[k] = pack_nib(sv[k]);
        } else {
            sv[k] = (f32x4){0.f, 0.f, 0.f, 0.f};
            nib[k] = 0u;
        }
    }

    // Mask words: nibbles of 8 consecutive lanes -> one u32 (32 elements).
    #pragma unroll
    for (int k = 0; k < 6; ++k) {
        unsigned part = nib[k] << (4 * (lane & 7));
        part |= __shfl_xor(part, 1);
        part |= __shfl_xor(part, 2);
        part |= __shfl_xor(part, 4);
        const int w = 8 * k + (lane >> 3);
        if ((lane & 7) == 0 && w < NW32) msk[wv][w] = part;
    }
    // Wave-internal LDS visibility (no cross-wave sharing -> no barrier).
    asm volatile("s_waitcnt lgkmcnt(0)" ::: "memory");

    // Row first/last valid index — uniform early-break scans (typ. 1 iter).
    int first = -1, last = -1;
    for (int w = 0; w < NW32; ++w) {
        unsigned mw = msk[wv][w];
        if (mw) { first = w * 32 + (__ffs(mw) - 1); break; }
    }
    if (first >= 0) {
        for (int w = NW32 - 1; w >= 0; --w) {
            unsigned mw = msk[wv][w];
            if (mw) { last = w * 32 + (31 - __clz(mw)); break; }
        }
    }
    if (lane == 0) rowflag[r] = (first >= 0) ? 1 : 0;

    // Fill NaN lanes and store.
    #pragma unroll
    for (int k = 0; k < 6; ++k) {
        const int c = 64 * k + lane;
        if (c >= NV) continue;
        f32x4 rv = sv[k];
        const unsigned nb_ = nib[k];
        if (first >= 0 && nb_ != 0xFu) {
            const int w = c >> 3;
            const unsigned mw   = msk[wv][w];
            const unsigned mwm1 = (w > 0)        ? msk[wv][w - 1] : 0u;
            const unsigned mwp1 = (w < NW32 - 1) ? msk[wv][w + 1] : 0u;
            const unsigned long long p64 =
                ((unsigned long long)mw   << 32) | mwm1;
            const unsigned long long n64 =
                ((unsigned long long)mwp1 << 32) | mw;
            float res[4] = {rv.x, rv.y, rv.z, rv.w};
            #pragma unroll
            for (int j = 0; j < 4; ++j) {
                if (!(nb_ & (1u << j))) {
                    const int i = 4 * c + j;
                    const int bpos = i & 31;
                    // prev: highest valid <= i within words w-1..w, else rare
                    // fallback scan, else wrap (last - LON).
                    unsigned long long pb = p64 & (~0ull >> (31 - bpos));
                    int prev;
                    if (pb) {
                        prev = (w - 1) * 32 + (63 - __clzll(pb));
                    } else {
                        int ww = w - 1; unsigned bits = 0u;
                        while (bits == 0u && ww > 0) bits = msk[wv][--ww];
                        prev = bits ? ww * 32 + (31 - __clz(bits))
                                    : (last - LON);
                    }
                    // next: lowest valid >= i within words w..w+1, else rare
                    // fallback scan, else wrap (first + LON).
                    unsigned long long nbits = n64 >> bpos;
                    int nxt;
                    if (nbits) {
                        nxt = i + (__ffsll((unsigned long long)nbits) - 1);
                    } else {
                        int ww = w + 1; unsigned bits = 0u;
                        while (bits == 0u && ww < NW32 - 1) bits = msk[wv][++ww];
                        nxt = bits ? ww * 32 + (__ffs(bits) - 1)
                                   : (first + LON);
                    }
                    float t  = (float)(i - prev)
                             * __builtin_amdgcn_rcpf((float)(nxt - prev));
                    float sp = s[wv][prev < 0    ? prev + LON : prev];
                    float sn = s[wv][nxt  >= LON ? nxt  - LON : nxt];
                    res[j] = fmaf(t, sn - sp, sp);
                }
            }
            rv.x = res[0]; rv.y = res[1]; rv.z = res[2]; rv.w = res[3];
        }
        __builtin_nontemporal_store(rv, (f32x4*)&out4[base4 + c]);
    }
}

// One block per batch. Reduce lastrow from rowflag, then copy the last valid
// row's filled values into tail rows at NaN positions. Benchmark input:
// lastrow == LAT-1 -> early exit after the tiny reduction.
__global__ __launch_bounds__(256) void fill_tail(const float* __restrict__ sst,
                                                 float*       __restrict__ out,
                                                 const unsigned char* __restrict__ rowflag) {
    const int b = blockIdx.x;
    const int tid = threadIdx.x;
    __shared__ int red[256];
    int lr = -1;
    for (int h = tid; h < LAT; h += 256)
        if (rowflag[b * LAT + h]) lr = h;
    red[tid] = lr;
    __syncthreads();
    for (int off = 128; off > 0; off >>= 1) {
        if (tid < off) red[tid] = max(red[tid], red[tid + off]);
        __syncthreads();
    }
    lr = red[0];
    if (lr < 0 || lr == LAT - 1) return;
    const size_t fb = ((size_t)b * LAT + lr) * LON;
    for (int h = lr + 1; h < LAT; ++h) {
        const size_t base = ((size_t)b * LAT + h) * LON;
        for (int i = tid; i < LON; i += 256) {
            float svv = sst[base + i];
            out[base + i] = is_nan_f(svv) ? out[fb + i] : svv;
        }
    }
}

extern "C" void kernel_launch(void* const* d_in, const int* in_sizes, int n_in,
                              void* d_out, int out_size, void* d_ws, size_t ws_size,
                              hipStream_t stream) {
    const f32x4* sst4 = (const f32x4*)d_in[0];
    f32x4* out4 = (f32x4*)d_out;
    unsigned char* rowflag = (unsigned char*)d_ws;   // NB*LAT = 23072 bytes

    fill_rows<<<(NB * LAT) / RPB, BS, 0, stream>>>(sst4, out4, rowflag);
    fill_tail<<<NB, 256, 0, stream>>>((const float*)d_in[0], (float*)d_out, rowflag);
}

// Round 7
// 284.602 us; speedup vs baseline: 1.0703x; 1.0177x over previous
//
#include <hip/hip_runtime.h>
#include <cstdint>

#define LON 1440
#define LAT 721
#define NB  32
#define NW32 45      // 1440/32 mask words per row
#define NV   360     // float4 chunks per row
#define BS   384     // 6 waves; threads 0..359 own one float4 chunk each
#define SPAD (LON + (LON >> 5))   // 1485 words: +1 pad word per 32 elements

typedef float f32x4 __attribute__((ext_vector_type(4)));

// Bank-spreading index: element e -> LDS word e + e/32. A gather at element
// stride 4 (64 lanes) then covers all 32 banks exactly 2-way (free).
__device__ __forceinline__ int sidx(int e) { return e + (e >> 5); }

__device__ __forceinline__ bool is_nan_f(float v) {
    return (__float_as_uint(v) & 0x7fffffffu) > 0x7f800000u;
}

// One block per (b,h) row. R0 structure (6 waves share one padded row strip,
// one barrier) + R6's 64-bit two-word prev/next window (clzll/ffsll) +
// bank-padded value LDS. Circular lerp at NaN points; rcp not precise div.
__global__ __launch_bounds__(BS) void fill_rows(const f32x4* __restrict__ sst4,
                                                f32x4*       __restrict__ out4,
                                                unsigned char* __restrict__ rowflag) {
    __shared__ float        s[SPAD];
    __shared__ unsigned int msk[NW32 + 3];

    const int r = blockIdx.x;
    const size_t base4 = (size_t)r * NV;
    const int tid = threadIdx.x;

    f32x4 sv = {0.f, 0.f, 0.f, 0.f};
    unsigned nib = 0u;
    if (tid < NV) {
        sv = sst4[base4 + tid];
        const int e0 = 4 * tid;
        const int w0 = sidx(e0);          // e0..e0+3 share one 32-block
        s[w0 + 0] = sv.x;
        s[w0 + 1] = sv.y;
        s[w0 + 2] = sv.z;
        s[w0 + 3] = sv.w;
        nib = (!is_nan_f(sv.x) ? 1u : 0u) | (!is_nan_f(sv.y) ? 2u : 0u)
            | (!is_nan_f(sv.z) ? 4u : 0u) | (!is_nan_f(sv.w) ? 8u : 0u);
    }
    // Combine nibbles of 8 consecutive threads into one mask word (elements
    // 32*(tid/8) .. 32*(tid/8)+31), OR-reduce within lane-groups of 8.
    unsigned part = nib << (4 * (tid & 7));
    part |= __shfl_xor(part, 1);
    part |= __shfl_xor(part, 2);
    part |= __shfl_xor(part, 4);
    if ((tid & 7) == 0 && tid < NV) msk[tid >> 3] = part;
    __syncthreads();

    // Row first/last valid index — uniform early-break scans (typ. 1 iter).
    int first = -1, last = -1;
    for (int w = 0; w < NW32; ++w) {
        unsigned mw = msk[w];
        if (mw) { first = w * 32 + (__ffs(mw) - 1); break; }
    }
    if (first >= 0) {
        for (int w = NW32 - 1; w >= 0; --w) {
            unsigned mw = msk[w];
            if (mw) { last = w * 32 + (31 - __clz(mw)); break; }
        }
    }
    if (tid == 0) rowflag[r] = (first >= 0) ? 1 : 0;

    if (tid < NV) {
        float res[4] = {sv.x, sv.y, sv.z, sv.w};
        if (first >= 0 && nib != 0xFu) {
            const int w = tid >> 3;
            const unsigned mw   = msk[w];
            const unsigned mwm1 = (w > 0)        ? msk[w - 1] : 0u;
            const unsigned mwp1 = (w < NW32 - 1) ? msk[w + 1] : 0u;
            const unsigned long long p64 =
                ((unsigned long long)mw   << 32) | mwm1;
            const unsigned long long n64 =
                ((unsigned long long)mwp1 << 32) | mw;
            #pragma unroll
            for (int j = 0; j < 4; ++j) {
                if (!(nib & (1u << j))) {
                    const int i = 4 * tid + j;
                    const int bpos = i & 31;
                    // prev: highest valid <= i within words w-1..w; rare
                    // fallback word scan; else wrap (last - LON).
                    unsigned long long pb = p64 & (~0ull >> (31 - bpos));
                    int prev;
                    if (pb) {
                        prev = (w - 1) * 32 + (63 - __clzll(pb));
                    } else {
                        int ww = w - 1; unsigned bits = 0u;
                        while (bits == 0u && ww > 0) bits = msk[--ww];
                        prev = bits ? ww * 32 + (31 - __clz(bits))
                                    : (last - LON);
                    }
                    // next: lowest valid >= i within words w..w+1; rare
                    // fallback word scan; else wrap (first + LON).
                    unsigned long long nbits = n64 >> bpos;
                    int nxt;
                    if (nbits) {
                        nxt = i + (__ffsll((unsigned long long)nbits) - 1);
                    } else {
                        int ww = w + 1; unsigned bits = 0u;
                        while (bits == 0u && ww < NW32 - 1) bits = msk[++ww];
                        nxt = bits ? ww * 32 + (__ffs(bits) - 1)
                                   : (first + LON);
                    }
                    float t  = (float)(i - prev)
                             * __builtin_amdgcn_rcpf((float)(nxt - prev));
                    float sp = s[sidx(prev < 0    ? prev + LON : prev)];
                    float sn = s[sidx(nxt  >= LON ? nxt  - LON : nxt)];
                    res[j] = fmaf(t, sn - sp, sp);
                }
            }
        }
        f32x4 rv;
        rv.x = res[0]; rv.y = res[1]; rv.z = res[2]; rv.w = res[3];
        __builtin_nontemporal_store(rv, (f32x4*)&out4[base4 + tid]);
    }
}

// One block per batch. Reduce lastrow from rowflag, then copy the last valid
// row's filled values into tail rows at NaN positions. Benchmark input:
// lastrow == LAT-1 -> early exit after the tiny reduction.
__global__ __launch_bounds__(256) void fill_tail(const float* __restrict__ sst,
                                                 float*       __restrict__ out,
                                                 const unsigned char* __restrict__ rowflag) {
    const int b = blockIdx.x;
    const int tid = threadIdx.x;
    __shared__ int red[256];
    int lr = -1;
    for (int h = tid; h < LAT; h += 256)
        if (rowflag[b * LAT + h]) lr = h;
    red[tid] = lr;
    __syncthreads();
    for (int off = 128; off > 0; off >>= 1) {
        if (tid < off) red[tid] = max(red[tid], red[tid + off]);
        __syncthreads();
    }
    lr = red[0];
    if (lr < 0 || lr == LAT - 1) return;
    const size_t fb = ((size_t)b * LAT + lr) * LON;
    for (int h = lr + 1; h < LAT; ++h) {
        const size_t base = ((size_t)b * LAT + h) * LON;
        for (int i = tid; i < LON; i += 256) {
            float svv = sst[base + i];
            out[base + i] = is_nan_f(svv) ? out[fb + i] : svv;
        }
    }
}

extern "C" void kernel_launch(void* const* d_in, const int* in_sizes, int n_in,
                              void* d_out, int out_size, void* d_ws, size_t ws_size,
                              hipStream_t stream) {
    const f32x4* sst4 = (const f32x4*)d_in[0];
    f32x4* out4 = (f32x4*)d_out;
    unsigned char* rowflag = (unsigned char*)d_ws;   // NB*LAT = 23072 bytes

    fill_rows<<<NB * LAT, BS, 0, stream>>>(sst4, out4, rowflag);
    fill_tail<<<NB, 256, 0, stream>>>((const float*)d_in[0], (float*)d_out, rowflag);
}